// Round 6
// baseline (10165.916 us; speedup 1.0000x reference)
//
#include <hip/hip_runtime.h>
#include <math.h>

#define SEQn 4096
#define EMBn 1024
#define Hn   512
#define G4n  2048
#define NTAGn 34
#define START_TAG 32
#define STOP_TAG 33
#define NEGV (-10000.0f)

typedef unsigned long long ull;
typedef __attribute__((ext_vector_type(8))) short bf16x8;
typedef __attribute__((ext_vector_type(4))) float f32x4;

// fp32 -> bf16 round-to-nearest-even (inputs are normal-range)
__device__ __forceinline__ unsigned f2bf(float f) {
  unsigned u = __float_as_uint(f);
  return (u + 0x7FFFu + ((u >> 16) & 1u)) >> 16;
}

// ---------------------------------------------------------------------------
// Kernel 1: xg = embed[sent] @ W_ih^T + (b_ih + b_hh), bf16 MFMA.
// 128x128 tile, BK=64, 256 thr (4 waves 2x2), T2 XOR-swizzled LDS.
// k-permutation identical for A and B frags (cancels in the contraction);
// C/D layout = m89-verified (col=lane&15, row=(lane>>4)*4+reg).
// ---------------------------------------------------------------------------
__global__ __launch_bounds__(256) void xg_mfma_kernel(
    const int* __restrict__ sent, const float* __restrict__ embed,
    const float* __restrict__ W, const float* __restrict__ bia,
    const float* __restrict__ bib, float* __restrict__ C)
{
  __shared__ unsigned short Alds[128 * 64];
  __shared__ unsigned short Blds[128 * 64];
  __shared__ int sent_s[128];

  const int tid = threadIdx.x;
  const int m0 = blockIdx.x * 128, n0 = blockIdx.y * 128;
  if (tid < 128) sent_s[tid] = sent[m0 + tid];

  const int w = tid >> 6, l = tid & 63;
  const int wm = w >> 1, wn = w & 1;

  const int srow = tid >> 4;          // 0..15 (row within each 16-row pass)
  const int scol = (tid & 15) * 4;    // float col 0..60 (16 lanes x 16B coalesced)

  f32x4 acc[4][4] = {};

  for (int kt = 0; kt < EMBn; kt += 64) {
    __syncthreads();                  // prev compute done (also covers sent_s)
#pragma unroll
    for (int i = 0; i < 8; ++i) {
      int row = srow + i * 16;
      float4 va = *(const float4*)(embed + (size_t)sent_s[row] * EMBn + kt + scol);
      float4 vb = *(const float4*)(W + (size_t)(n0 + row) * EMBn + kt + scol);
      unsigned pa0 = f2bf(va.x) | (f2bf(va.y) << 16);
      unsigned pa1 = f2bf(va.z) | (f2bf(va.w) << 16);
      unsigned pb0 = f2bf(vb.x) | (f2bf(vb.y) << 16);
      unsigned pb1 = f2bf(vb.z) | (f2bf(vb.w) << 16);
      int idx = (row * 64 + scol) ^ ((row & 7) << 3);   // T2 swizzle (16B granule)
      *(uint2*)&Alds[idx] = make_uint2(pa0, pa1);
      *(uint2*)&Blds[idx] = make_uint2(pb0, pb1);
    }
    __syncthreads();
#pragma unroll
    for (int kk = 0; kk < 2; ++kk) {
      bf16x8 af[4], bfr[4];
      const int kus = kk * 32 + (l >> 4) * 8;
#pragma unroll
      for (int mi = 0; mi < 4; ++mi) {
        int row = wm * 64 + mi * 16 + (l & 15);
        int idx = (row * 64 + kus) ^ ((row & 7) << 3);
        af[mi] = *(bf16x8*)&Alds[idx];
      }
#pragma unroll
      for (int ni = 0; ni < 4; ++ni) {
        int row = wn * 64 + ni * 16 + (l & 15);
        int idx = (row * 64 + kus) ^ ((row & 7) << 3);
        bfr[ni] = *(bf16x8*)&Blds[idx];
      }
#pragma unroll
      for (int mi = 0; mi < 4; ++mi)
#pragma unroll
        for (int ni = 0; ni < 4; ++ni)
          acc[mi][ni] = __builtin_amdgcn_mfma_f32_16x16x32_bf16(
              af[mi], bfr[ni], acc[mi][ni], 0, 0, 0);
    }
  }

  const int cm = m0 + wm * 64 + (l >> 4) * 4;
  const int cn = n0 + wn * 64 + (l & 15);
#pragma unroll
  for (int ni = 0; ni < 4; ++ni) {
    float bv = bia[cn + ni * 16] + bib[cn + ni * 16];
#pragma unroll
    for (int mi = 0; mi < 4; ++mi)
#pragma unroll
      for (int r = 0; r < 4; ++r)
        C[(size_t)(cm + mi * 16 + r) * G4n + cn + ni * 16] = acc[mi][ni][r] + bv;
  }
}

// ---------------------------------------------------------------------------
// L2-coherent 8B load (bypasses L1 via sc0, served by this XCD's L2).
// ---------------------------------------------------------------------------
__device__ __forceinline__ ull load_l2(const ull* p) {
  ull v;
  asm volatile("global_load_dwordx2 %0, %1, off sc0\n\t"
               "s_waitcnt vmcnt(0)"
               : "=v"(v) : "v"(p) : "memory");
  return v;
}

// ---------------------------------------------------------------------------
// Kernel 2: persistent bidirectional LSTM, v6 — XCC_ID self-placement.
// 256 blocks launched; block reads hwreg XCC_ID: XCD0 blocks claim the 16
// fwd roles, XCD1 the 16 bwd roles (atomic tickets). All other blocks sleep
// ~25us then fill any unclaimed roles (deadlock-free under any mapping or
// garbage hwreg; role assignment only affects speed, outputs identical).
// Same-XCD placement makes the fast L2 exchange real: poll is fast-dominant
// (8x sc0 polls per slow LLC check).
// ---------------------------------------------------------------------------
__global__ __launch_bounds__(1024) void lstm_kernel(
    const float* __restrict__ xg_f, const float* __restrict__ xg_b,
    const float* __restrict__ w_hh_f, const float* __restrict__ w_hh_b,
    const float* __restrict__ h0, const float* __restrict__ c0,
    float* __restrict__ hs, ull* __restrict__ hslow, ull* __restrict__ hfast,
    unsigned* __restrict__ tick)
{
  __shared__ int role_s;
  if (threadIdx.x == 0) {
    unsigned xcc = __builtin_amdgcn_s_getreg(6164) & 7u; // hwreg(XCC_ID=20,0,4)
    int r = -1;
    if (xcc == 0u)      { unsigned t = atomicAdd(&tick[0], 1u); if (t < 16u) r = (int)t; }
    else if (xcc == 1u) { unsigned t = atomicAdd(&tick[1], 1u); if (t < 16u) r = 16 + (int)t; }
    if (r < 0) {
      for (int i = 0; i < 8; ++i) __builtin_amdgcn_s_sleep(127);  // ~25us
      unsigned t = atomicAdd(&tick[0], 1u);
      if (t < 16u) r = (int)t;
      else { t = atomicAdd(&tick[1], 1u); if (t < 16u) r = 16 + (int)t; }
    }
    role_s = r;
  }
  __syncthreads();
  const int role = role_s;
  if (role < 0) return;               // unneeded placement block
  const int dir = role >> 4;
  const int blk = role & 15;
  const int hbase = blk * 32;
  const float* W  = dir ? w_hh_b : w_hh_f;
  const float* xg = dir ? xg_b : xg_f;
  ull* slow_d = hslow + (size_t)dir * 4 * Hn;   // [slot][512]
  ull* fast_d = hfast + (size_t)dir * 4 * Hn;

  const int t = threadIdx.x;
  const int w = t >> 6;        // wave id; wave w owns h-segment [w*32, w*32+32)
  const int l = t & 63;        // lane; local gate rows {l, l+64}
  const bool isTW = (w == blk);   // tail wave: its h-segment is local

  const int R0 = (l >> 5) * Hn + hbase + (l & 31);            // rows 0..63   (i|f)
  const int R1 = ((l + 64) >> 5) * Hn + hbase + (l & 31);     // rows 64..127 (g|o)
  float4 wreg[16];
  {
    const float* wr0 = W + (size_t)R0 * Hn + w * 32;
    const float* wr1 = W + (size_t)R1 * Hn + w * 32;
#pragma unroll
    for (int jj = 0; jj < 8; ++jj) {
      wreg[jj]     = *(const float4*)(wr0 + jj * 4);
      wreg[8 + jj] = *(const float4*)(wr1 + jj * 4);
    }
  }

  __shared__ __align__(16) float h_lds[Hn];          // wave-private segments
  __shared__ float part[2][16 * 130];                // [parity][wave][row]

  if (isTW) __builtin_amdgcn_s_setprio(1);

  float c_reg = 0.f;
  float xg_cur0 = 0.f, xg_cur1 = 0.f, xg_nxt0 = 0.f, xg_nxt1 = 0.f;
  if (isTW) {
    if (l < 32) c_reg = c0[dir * Hn + hbase + l];
    const int s0 = dir ? (SEQn - 1) : 0;
    xg_cur0 = xg[(size_t)s0 * G4n + R0];
    xg_cur1 = xg[(size_t)s0 * G4n + R1];
  }
  if (l < 32) h_lds[w * 32 + l] = h0[dir * Hn + w * 32 + l];

  for (int k = 0; k < SEQn; ++k) {
    const int par = k & 1;
    const int s = dir ? (SEQn - 1 - k) : k;

    // TW: prefetch xg for NEXT step (full-step distance covers HBM latency)
    if (isTW && (k + 1 < SEQn)) {
      const int s1 = dir ? (SEQn - 2 - k) : (k + 1);
      xg_nxt0 = xg[(size_t)s1 * G4n + R0];
      xg_nxt1 = xg[(size_t)s1 * G4n + R1];
    }

    // non-tail waves: poll own segment; fast L2 path dominant, slow fallback
    if (!isTW && k > 0) {
      if (l < 32) {
        const size_t idx = (size_t)(k & 3) * Hn + w * 32 + l;
        const ull* fp = fast_d + idx;
        ull* sp = slow_d + idx;
        ull v;
        for (;;) {
          bool got = false;
#pragma unroll
          for (int it = 0; it < 8; ++it) {
            v = load_l2(fp);
            if ((unsigned)(v >> 32) == (unsigned)k) { got = true; break; }
          }
          if (got) break;
          v = __hip_atomic_load(sp, __ATOMIC_RELAXED, __HIP_MEMORY_SCOPE_AGENT);
          if ((unsigned)(v >> 32) == (unsigned)k) break;
        }
        h_lds[w * 32 + l] = __uint_as_float((unsigned)v);
      }
    }
    // intra-wave lgkmcnt ordering makes the writes visible to the reads below

    // dot: wave-uniform broadcast reads of own segment, 2 rows per lane
    float a0 = 0.f, a1 = 0.f;
    {
      const float* hseg = h_lds + w * 32;
#pragma unroll
      for (int jj = 0; jj < 8; ++jj) {
        float4 hv = *(const float4*)(hseg + jj * 4);
        float4 wa = wreg[jj], wb = wreg[8 + jj];
        a0 += wa.x * hv.x + wa.y * hv.y + wa.z * hv.z + wa.w * hv.w;
        a1 += wb.x * hv.x + wb.y * hv.y + wb.z * hv.z + wb.w * hv.w;
      }
    }
    part[par][w * 130 + l] = a0;
    part[par][w * 130 + 64 + l] = a1;
    __syncthreads();   // the ONLY barrier per step

    // tail: reduce 16 partials, activations, cell update, publish-first
    if (isTW) {
      float g0 = xg_cur0, g1 = xg_cur1;
#pragma unroll
      for (int ww = 0; ww < 16; ++ww) {
        g0 += part[par][ww * 130 + l];
        g1 += part[par][ww * 130 + 64 + l];
      }
      float e0 = __expf(-g0);
      float act0 = 1.f / (1.f + e0);
      float z = (l < 32) ? 2.f * g1 : g1;
      float e1 = __expf(-z);
      float sg = 1.f / (1.f + e1);
      float act1 = (l < 32) ? (2.f * sg - 1.f) : sg;

      float p0 = __shfl_xor(act0, 32);   // lane e<32 gets f(e)
      float p1 = __shfl_xor(act1, 32);   // lane e<32 gets o(e)
      if (l < 32) {
        float iv = act0, gv = act1, fv = p0, ov = p1;
        float c = fv * c_reg + iv * gv;
        c_reg = c;
        float e2 = __expf(-2.f * c);
        float h = ov * (1.f - e2) / (1.f + e2);
        if (k + 1 < SEQn) {
          ull pv = ((ull)(unsigned)(k + 1) << 32) | (ull)__float_as_uint(h);
          const size_t pidx = (size_t)((k + 1) & 3) * Hn + hbase + l;
          // fast first: visible via same-XCD L2 asap
          __hip_atomic_store(fast_d + pidx, pv, __ATOMIC_RELAXED,
                             __HIP_MEMORY_SCOPE_WORKGROUP);
          __hip_atomic_store(slow_d + pidx, pv, __ATOMIC_RELAXED,
                             __HIP_MEMORY_SCOPE_AGENT);
        }
        h_lds[hbase + l] = h;            // own segment for next step's dot
        hs[(size_t)s * 1024 + dir * Hn + hbase + l] = h;
      }
      xg_cur0 = xg_nxt0; xg_cur1 = xg_nxt1;
    }
  }
}

// ---------------------------------------------------------------------------
// Kernel 3: feats = [hs_f|hs_b] @ W_out^T + b_out     (4096 x 34)
// ---------------------------------------------------------------------------
__global__ __launch_bounds__(64) void feats_kernel(
    const float* __restrict__ hs, const float* __restrict__ W_out,
    const float* __restrict__ b_out, float* __restrict__ feats)
{
  const int tq = blockIdx.x;
  const int lane = threadIdx.x;
  const float* hrow = hs + (size_t)tq * 1024;
  float4 hv[4];
#pragma unroll
  for (int i = 0; i < 4; ++i) hv[i] = *(const float4*)(hrow + lane * 16 + i * 4);

  for (int tag = 0; tag < NTAGn; ++tag) {
    const float* wrow = W_out + (size_t)tag * 1024 + lane * 16;
    float s = 0.f;
#pragma unroll
    for (int i = 0; i < 4; ++i) {
      float4 wv = *(const float4*)(wrow + i * 4);
      s += hv[i].x * wv.x + hv[i].y * wv.y + hv[i].z * wv.z + hv[i].w * wv.w;
    }
#pragma unroll
    for (int off = 32; off; off >>= 1) s += __shfl_xor(s, off);
    if (lane == 0) feats[(size_t)tq * NTAGn + tag] = s + b_out[tag];
  }
}

// ---------------------------------------------------------------------------
// Kernel 4: Viterbi forward + backtrack. Single wave; lane = tag.
// ---------------------------------------------------------------------------
__global__ __launch_bounds__(64) void viterbi_kernel(
    const float* __restrict__ feats, const float* __restrict__ logT,
    float* __restrict__ out)
{
  extern __shared__ unsigned char bp[];   // SEQn * NTAGn bytes
  __shared__ float fv_s[36];
  __shared__ float red[36];
  const int lane = threadIdx.x;
  const bool active = lane < NTAGn;

  float Trow[36];
  if (active) {
#pragma unroll
    for (int j = 0; j < NTAGn; ++j) Trow[j] = logT[lane * NTAGn + j];
    Trow[34] = NEGV; Trow[35] = NEGV;
    fv_s[lane] = (lane == START_TAG) ? 0.f : NEGV;
  }
  if (lane == 0) { fv_s[34] = NEGV; fv_s[35] = NEGV; }
  __syncthreads();

  float ft = active ? feats[lane] : 0.f;
  for (int tv = 0; tv < SEQn; ++tv) {
    float best = -3.4e38f; int bj = 0;
    float ftn = 0.f;
    if (active) {
      float sc[36];
#pragma unroll
      for (int q = 0; q < 9; ++q) {
        float4 f4 = *(const float4*)&fv_s[q * 4];
        sc[q*4+0] = f4.x + Trow[q*4+0];
        sc[q*4+1] = f4.y + Trow[q*4+1];
        sc[q*4+2] = f4.z + Trow[q*4+2];
        sc[q*4+3] = f4.w + Trow[q*4+3];
      }
      best = sc[0];
#pragma unroll
      for (int j = 1; j < 36; ++j) { if (sc[j] > best) { best = sc[j]; bj = j; } }
      if (tv + 1 < SEQn) ftn = feats[(size_t)(tv + 1) * NTAGn + lane];
    }
    if (active) {
      fv_s[lane] = best + ft;
      bp[tv * NTAGn + lane] = (unsigned char)bj;
    }
    __threadfence_block();
    ft = ftn;
  }

  if (active) red[lane] = fv_s[lane] + logT[STOP_TAG * NTAGn + lane];
  __threadfence_block();
  __syncthreads();
  if (lane == 0) {
    float bestv = -3.4e38f; int bi = 0;
#pragma unroll
    for (int i = 0; i < NTAGn; ++i) { float v = red[i]; if (v > bestv) { bestv = v; bi = i; } }
    out[0] = bestv;
    int tag = bi;
    out[1 + SEQn - 1] = (float)tag;
    for (int tv = SEQn - 1; tv >= 1; --tv) {
      tag = bp[tv * NTAGn + tag];
      out[tv] = (float)tag;
    }
  }
}

// ---------------------------------------------------------------------------
extern "C" void kernel_launch(void* const* d_in, const int* in_sizes, int n_in,
                              void* d_out, int out_size, void* d_ws, size_t ws_size,
                              hipStream_t stream) {
  const int*   sent   = (const int*)d_in[0];
  const float* embed  = (const float*)d_in[1];
  const float* w_ih_f = (const float*)d_in[2];
  const float* w_hh_f = (const float*)d_in[3];
  const float* b_ih_f = (const float*)d_in[4];
  const float* b_hh_f = (const float*)d_in[5];
  const float* w_ih_b = (const float*)d_in[6];
  const float* w_hh_b = (const float*)d_in[7];
  const float* b_ih_b = (const float*)d_in[8];
  const float* b_hh_b = (const float*)d_in[9];
  const float* W_out  = (const float*)d_in[10];
  const float* b_out  = (const float*)d_in[11];
  const float* logT   = (const float*)d_in[12];
  const float* h0     = (const float*)d_in[13];
  const float* c0     = (const float*)d_in[14];
  float* out = (float*)d_out;

  char* ws = (char*)d_ws;
  size_t off = 0;
  float* xg_f  = (float*)(ws + off); off += (size_t)SEQn * G4n * 4;
  float* xg_b  = (float*)(ws + off); off += (size_t)SEQn * G4n * 4;
  float* hs    = (float*)(ws + off); off += (size_t)SEQn * 1024 * 4;
  float* feats = (float*)(ws + off); off += (size_t)SEQn * NTAGn * 4;
  ull*   hslow = (ull*)(ws + off);   off += 2 * 4 * Hn * 8;   // 32 KiB
  ull*   hfast = (ull*)(ws + off);   off += 2 * 4 * Hn * 8;   // 32 KiB
  unsigned* tick = (unsigned*)(ws + off); off += 256;

  // clear exchange tags + role tickets every launch (graph-replay safe)
  hipMemsetAsync(hslow, 0, 2 * 4 * Hn * 8 * 2 + 256, stream);

  dim3 gg(SEQn / 128, G4n / 128);
  xg_mfma_kernel<<<gg, 256, 0, stream>>>(sent, embed, w_ih_f, b_ih_f, b_hh_f, xg_f);
  xg_mfma_kernel<<<gg, 256, 0, stream>>>(sent, embed, w_ih_b, b_ih_b, b_hh_b, xg_b);

  lstm_kernel<<<256, 1024, 0, stream>>>(xg_f, xg_b, w_hh_f, w_hh_b, h0, c0, hs,
                                        hslow, hfast, tick);

  feats_kernel<<<SEQn, 64, 0, stream>>>(hs, W_out, b_out, feats);

  static const int dyn_lds = SEQn * NTAGn;   // 139264 bytes
  hipFuncSetAttribute((const void*)viterbi_kernel,
                      hipFuncAttributeMaxDynamicSharedMemorySize, dyn_lds);
  viterbi_kernel<<<1, 64, dyn_lds, stream>>>(feats, logT, out);
}